// Round 8
// baseline (396.738 us; speedup 1.0000x reference)
//
#include <hip/hip_runtime.h>
#include <hip/hip_bf16.h>
#include <hip/hip_fp16.h>

typedef unsigned short u16;
typedef unsigned int u32;
typedef __attribute__((ext_vector_type(8))) short bf16x8;
typedef __attribute__((ext_vector_type(4))) float f32x4;

#define Q_N  6400
#define S_N  7979
#define BEV  80

__device__ __forceinline__ float ubf(u16 u) {
    return __uint_as_float(((u32)u) << 16);
}
__device__ __forceinline__ u16 bfrn(float x) {
    u32 b = __float_as_uint(x);
    return (u16)((b + 0x7FFFu + ((b >> 16) & 1u)) >> 16);
}
__device__ __forceinline__ float f16tof(u16 u) {
    __half h; *(u16*)&h = u; return __half2float(h);
}
__device__ __forceinline__ u16 ftof16(float f) {
    __half h = __float2half(f); return *(u16*)&h;
}

// =================== BN=128 GEMM body (BM=64, BK=32) — for N=768/512/128 ===================
template <int AIN, int RELU, int OUTMODE, int SM4, int SM32>
__device__ __forceinline__ void gemm_body(
    const void* __restrict__ A, const u16* __restrict__ WhT, const u16* __restrict__ WlT,
    const float* __restrict__ bias, const float* __restrict__ bias2,
    void* __restrict__ Cout, int M, int N, int K, int bx, int by,
    u16* Ah, u16* Al, u16* Wh, u16* Wl)
{
    const int tid  = threadIdx.x;
    const int lane = tid & 63;
    const int wave = tid >> 6;
    const int wm = (wave >> 1) * 32, wn = (wave & 1) * 64;
    const int m0 = by * 64, n0 = bx * 128;
    const int arow = tid >> 2, ak = (tid & 3) * 8;
    const int wrow = tid >> 1, wk = (tid & 1) * 16;
    const int fr = lane & 15, gq = lane >> 4;

    f32x4 acc[8];
    #pragma unroll
    for (int i = 0; i < 8; ++i) acc[i] = (f32x4)(0.f);

    for (int k0 = 0; k0 < K; k0 += 32) {
        {
            const bool okr = (m0 + arow) < M;
            float vals[8];
            if (AIN == 0) {
                const float* ap = (const float*)A + (size_t)(m0 + arow) * K + k0 + ak;
                float4 v0 = okr ? *(const float4*)(ap)     : make_float4(0.f, 0.f, 0.f, 0.f);
                float4 v1 = okr ? *(const float4*)(ap + 4) : make_float4(0.f, 0.f, 0.f, 0.f);
                vals[0] = v0.x; vals[1] = v0.y; vals[2] = v0.z; vals[3] = v0.w;
                vals[4] = v1.x; vals[5] = v1.y; vals[6] = v1.z; vals[7] = v1.w;
            } else {
                const u16* ap = (const u16*)A + (size_t)(m0 + arow) * K + k0 + ak;
                uint4 u = okr ? *(const uint4*)ap : make_uint4(0, 0, 0, 0);
                const __half2* hp = (const __half2*)&u;
                #pragma unroll
                for (int i = 0; i < 4; ++i) {
                    float2 f = __half22float2(hp[i]);
                    vals[2 * i] = f.x; vals[2 * i + 1] = f.y;
                }
            }
            u16 hb[8], lb[8];
            #pragma unroll
            for (int i = 0; i < 8; ++i) {
                hb[i] = bfrn(vals[i]);
                lb[i] = bfrn(vals[i] - ubf(hb[i]));
            }
            *(ushort4*)(&Ah[arow * 40 + ak])     = *(ushort4*)&hb[0];
            *(ushort4*)(&Ah[arow * 40 + ak + 4]) = *(ushort4*)&hb[4];
            *(ushort4*)(&Al[arow * 40 + ak])     = *(ushort4*)&lb[0];
            *(ushort4*)(&Al[arow * 40 + ak + 4]) = *(ushort4*)&lb[4];
        }
        {
            const size_t wo = (size_t)(n0 + wrow) * K + k0 + wk;
            *(uint4*)&Wh[wrow * 40 + wk]     = *(const uint4*)(WhT + wo);
            *(uint4*)&Wh[wrow * 40 + wk + 8] = *(const uint4*)(WhT + wo + 8);
            *(uint4*)&Wl[wrow * 40 + wk]     = *(const uint4*)(WlT + wo);
            *(uint4*)&Wl[wrow * 40 + wk + 8] = *(const uint4*)(WlT + wo + 8);
        }
        __syncthreads();
        bf16x8 fah[2], fal[2], fwh[4], fwl[4];
        #pragma unroll
        for (int i = 0; i < 2; ++i) {
            fah[i] = *(const bf16x8*)&Ah[(wm + i * 16 + fr) * 40 + gq * 8];
            fal[i] = *(const bf16x8*)&Al[(wm + i * 16 + fr) * 40 + gq * 8];
        }
        #pragma unroll
        for (int j = 0; j < 4; ++j) {
            fwh[j] = *(const bf16x8*)&Wh[(wn + j * 16 + fr) * 40 + gq * 8];
            fwl[j] = *(const bf16x8*)&Wl[(wn + j * 16 + fr) * 40 + gq * 8];
        }
        #pragma unroll
        for (int i = 0; i < 2; ++i)
            #pragma unroll
            for (int j = 0; j < 4; ++j) {
                acc[i * 4 + j] = __builtin_amdgcn_mfma_f32_16x16x32_bf16(fah[i], fwh[j], acc[i * 4 + j], 0, 0, 0);
                acc[i * 4 + j] = __builtin_amdgcn_mfma_f32_16x16x32_bf16(fal[i], fwh[j], acc[i * 4 + j], 0, 0, 0);
                acc[i * 4 + j] = __builtin_amdgcn_mfma_f32_16x16x32_bf16(fah[i], fwl[j], acc[i * 4 + j], 0, 0, 0);
            }
        __syncthreads();
    }
    const int g4r = gq * 4;
    float bv[4];
    #pragma unroll
    for (int j = 0; j < 4; ++j) {
        int col = n0 + wn + j * 16 + fr;
        if (bias2) bv[j] = (col < 512) ? bias[col] : bias2[col - 512];
        else       bv[j] = bias ? bias[col] : 0.f;
    }
    const bool do_sm32 = SM32 && ((n0 + wn) >= 512);
    const bool do_sm4  = SM4 && (wn == 64);
    #pragma unroll
    for (int i = 0; i < 2; ++i) {
        #pragma unroll
        for (int r = 0; r < 4; ++r) {
            const int row = m0 + wm + i * 16 + g4r + r;
            float v0 = acc[i * 4 + 0][r] + bv[0];
            float v1 = acc[i * 4 + 1][r] + bv[1];
            float v2 = acc[i * 4 + 2][r] + bv[2];
            float v3 = acc[i * 4 + 3][r] + bv[3];
            if (RELU) {
                v0 = fmaxf(v0, 0.f); v1 = fmaxf(v1, 0.f);
                v2 = fmaxf(v2, 0.f); v3 = fmaxf(v3, 0.f);
            }
            if (SM4 && do_sm4) {
                float m0q = fmaxf(v0, __shfl_xor(v0, 1));
                m0q = fmaxf(m0q, __shfl_xor(m0q, 2));
                float e0 = __expf(v0 - m0q);
                float s0 = e0 + __shfl_xor(e0, 1);
                s0 += __shfl_xor(s0, 2);
                v0 = e0 / s0;
                float m1q = fmaxf(v1, __shfl_xor(v1, 1));
                m1q = fmaxf(m1q, __shfl_xor(m1q, 2));
                float e1 = __expf(v1 - m1q);
                float s1 = e1 + __shfl_xor(e1, 1);
                s1 += __shfl_xor(s1, 2);
                v1 = e1 / s1;
                v2 = 0.f; v3 = 0.f;
            }
            if (SM32 && do_sm32) {
                float ma = fmaxf(v0, v1);
                ma = fmaxf(ma, __shfl_xor(ma, 1));
                ma = fmaxf(ma, __shfl_xor(ma, 2));
                ma = fmaxf(ma, __shfl_xor(ma, 4));
                ma = fmaxf(ma, __shfl_xor(ma, 8));
                float e0 = __expf(v0 - ma), e1 = __expf(v1 - ma);
                float sa = e0 + e1;
                sa += __shfl_xor(sa, 1);
                sa += __shfl_xor(sa, 2);
                sa += __shfl_xor(sa, 4);
                sa += __shfl_xor(sa, 8);
                float ia = 1.f / sa;
                v0 = e0 * ia; v1 = e1 * ia;
                float mb = fmaxf(v2, v3);
                mb = fmaxf(mb, __shfl_xor(mb, 1));
                mb = fmaxf(mb, __shfl_xor(mb, 2));
                mb = fmaxf(mb, __shfl_xor(mb, 4));
                mb = fmaxf(mb, __shfl_xor(mb, 8));
                float e2 = __expf(v2 - mb), e3 = __expf(v3 - mb);
                float sb = e2 + e3;
                sb += __shfl_xor(sb, 1);
                sb += __shfl_xor(sb, 2);
                sb += __shfl_xor(sb, 4);
                sb += __shfl_xor(sb, 8);
                float ib = 1.f / sb;
                v2 = e2 * ib; v3 = e3 * ib;
            }
            if (row < M) {
                const int colb = n0 + wn + fr;
                if (OUTMODE == 1) {
                    u16* cp = (u16*)Cout + (size_t)row * N;
                    cp[colb]      = ftof16(v0);
                    cp[colb + 16] = ftof16(v1);
                    cp[colb + 32] = ftof16(v2);
                    cp[colb + 48] = ftof16(v3);
                } else {
                    float* cp = (float*)Cout + (size_t)row * N;
                    cp[colb]      = v0;
                    cp[colb + 16] = v1;
                    cp[colb + 32] = v2;
                    cp[colb + 48] = v3;
                }
            }
        }
    }
}

// =================== BN=256 GEMM body (BM=64, BK=32), N=256 only ===================
// OUTMODE: 0=f32, 1=f16 row-major, 2=f16 head-major val. LN: fused layernorm
// (res/gam/bet), writes f32 LN output.
template <int AIN, int OUTMODE, int LN>
__device__ __forceinline__ void gemm_body256(
    const void* __restrict__ A, const u16* __restrict__ WhT, const u16* __restrict__ WlT,
    const float* __restrict__ bias, const float* __restrict__ res,
    const float* __restrict__ gam, const float* __restrict__ bet,
    void* __restrict__ Cout, int M, int K, int by, u16* smem)
{
    u16* Ah = smem;            // 64*40
    u16* Al = smem + 2560;     // 64*40
    u16* Wh = smem + 5120;     // 256*40
    u16* Wl = smem + 15360;    // 256*40
    const int tid  = threadIdx.x;
    const int lane = tid & 63;
    const int wave = tid >> 6;
    const int wm = (wave >> 1) * 32, wn = (wave & 1) * 128;
    const int m0 = by * 64;
    const int arow = tid >> 2, ak = (tid & 3) * 8;
    const int fr = lane & 15, gq = lane >> 4;

    f32x4 acc[16];
    #pragma unroll
    for (int i = 0; i < 16; ++i) acc[i] = (f32x4)(0.f);

    for (int k0 = 0; k0 < K; k0 += 32) {
        {
            const bool okr = (m0 + arow) < M;
            float vals[8];
            if (AIN == 0) {
                const float* ap = (const float*)A + (size_t)(m0 + arow) * K + k0 + ak;
                float4 v0 = okr ? *(const float4*)(ap)     : make_float4(0.f, 0.f, 0.f, 0.f);
                float4 v1 = okr ? *(const float4*)(ap + 4) : make_float4(0.f, 0.f, 0.f, 0.f);
                vals[0] = v0.x; vals[1] = v0.y; vals[2] = v0.z; vals[3] = v0.w;
                vals[4] = v1.x; vals[5] = v1.y; vals[6] = v1.z; vals[7] = v1.w;
            } else {
                const u16* ap = (const u16*)A + (size_t)(m0 + arow) * K + k0 + ak;
                uint4 u = okr ? *(const uint4*)ap : make_uint4(0, 0, 0, 0);
                const __half2* hp = (const __half2*)&u;
                #pragma unroll
                for (int i = 0; i < 4; ++i) {
                    float2 f = __half22float2(hp[i]);
                    vals[2 * i] = f.x; vals[2 * i + 1] = f.y;
                }
            }
            u16 hb[8], lb[8];
            #pragma unroll
            for (int i = 0; i < 8; ++i) {
                hb[i] = bfrn(vals[i]);
                lb[i] = bfrn(vals[i] - ubf(hb[i]));
            }
            *(ushort4*)(&Ah[arow * 40 + ak])     = *(ushort4*)&hb[0];
            *(ushort4*)(&Ah[arow * 40 + ak + 4]) = *(ushort4*)&hb[4];
            *(ushort4*)(&Al[arow * 40 + ak])     = *(ushort4*)&lb[0];
            *(ushort4*)(&Al[arow * 40 + ak + 4]) = *(ushort4*)&lb[4];
        }
        {
            const size_t wo = (size_t)tid * K + k0;
            const uint4* sh = (const uint4*)(WhT + wo);
            const uint4* sl = (const uint4*)(WlT + wo);
            uint4* dh = (uint4*)&Wh[tid * 40];
            uint4* dl = (uint4*)&Wl[tid * 40];
            dh[0] = sh[0]; dh[1] = sh[1]; dh[2] = sh[2]; dh[3] = sh[3];
            dl[0] = sl[0]; dl[1] = sl[1]; dl[2] = sl[2]; dl[3] = sl[3];
        }
        __syncthreads();
        bf16x8 fah[2], fal[2];
        #pragma unroll
        for (int i = 0; i < 2; ++i) {
            fah[i] = *(const bf16x8*)&Ah[(wm + i * 16 + fr) * 40 + gq * 8];
            fal[i] = *(const bf16x8*)&Al[(wm + i * 16 + fr) * 40 + gq * 8];
        }
        #pragma unroll
        for (int jg = 0; jg < 2; ++jg) {
            bf16x8 fwh[4], fwl[4];
            #pragma unroll
            for (int j = 0; j < 4; ++j) {
                fwh[j] = *(const bf16x8*)&Wh[(wn + jg * 64 + j * 16 + fr) * 40 + gq * 8];
                fwl[j] = *(const bf16x8*)&Wl[(wn + jg * 64 + j * 16 + fr) * 40 + gq * 8];
            }
            #pragma unroll
            for (int i = 0; i < 2; ++i)
                #pragma unroll
                for (int j = 0; j < 4; ++j) {
                    int a = i * 8 + jg * 4 + j;
                    acc[a] = __builtin_amdgcn_mfma_f32_16x16x32_bf16(fah[i], fwh[j], acc[a], 0, 0, 0);
                    acc[a] = __builtin_amdgcn_mfma_f32_16x16x32_bf16(fal[i], fwh[j], acc[a], 0, 0, 0);
                    acc[a] = __builtin_amdgcn_mfma_f32_16x16x32_bf16(fah[i], fwl[j], acc[a], 0, 0, 0);
                }
        }
        __syncthreads();
    }
    const int g4r = gq * 4;
    if (LN) {
        u16* lnbuf = smem;                       // 64*256 u16 = 32KB
        float* sred = (float*)(smem + 16384);    // 256 floats
        // pass 1: v = acc + bias + res; stats; stash f16
        #pragma unroll
        for (int i = 0; i < 2; ++i) {
            #pragma unroll
            for (int r = 0; r < 4; ++r) {
                const int rl = wm + i * 16 + g4r + r;
                const int row = m0 + rl;
                float s = 0.f, ss = 0.f;
                #pragma unroll
                for (int j = 0; j < 8; ++j) {
                    int col = wn + j * 16 + fr;
                    float v = acc[i * 8 + j][r] + bias[col] + res[(size_t)row * 256 + col];
                    s += v; ss += v * v;
                    lnbuf[rl * 256 + col] = ftof16(v);
                }
                s += __shfl_xor(s, 1); ss += __shfl_xor(ss, 1);
                s += __shfl_xor(s, 2); ss += __shfl_xor(ss, 2);
                s += __shfl_xor(s, 4); ss += __shfl_xor(ss, 4);
                s += __shfl_xor(s, 8); ss += __shfl_xor(ss, 8);
                if (fr == 0) {
                    sred[rl * 2 + (wave & 1)] = s;
                    sred[128 + rl * 2 + (wave & 1)] = ss;
                }
            }
        }
        __syncthreads();
        #pragma unroll
        for (int i = 0; i < 2; ++i) {
            #pragma unroll
            for (int r = 0; r < 4; ++r) {
                const int rl = wm + i * 16 + g4r + r;
                const int row = m0 + rl;
                float S  = sred[rl * 2] + sred[rl * 2 + 1];
                float SS = sred[128 + rl * 2] + sred[128 + rl * 2 + 1];
                float mean = S * (1.f / 256.f);
                float var = SS * (1.f / 256.f) - mean * mean;
                float rstd = rsqrtf(var + 1e-5f);
                #pragma unroll
                for (int j = 0; j < 8; ++j) {
                    int col = wn + j * 16 + fr;
                    float v = f16tof(lnbuf[rl * 256 + col]);
                    ((float*)Cout)[(size_t)row * 256 + col] =
                        (v - mean) * rstd * gam[col] + bet[col];
                }
            }
        }
    } else {
        #pragma unroll
        for (int i = 0; i < 2; ++i) {
            #pragma unroll
            for (int r = 0; r < 4; ++r) {
                const int row = m0 + wm + i * 16 + g4r + r;
                if (row >= M) continue;
                int vi = 0, si = 0;
                if (OUTMODE == 2) { vi = row / S_N; si = row - vi * S_N; }
                #pragma unroll
                for (int j = 0; j < 8; ++j) {
                    int col = wn + j * 16 + fr;
                    float v = acc[i * 8 + j][r] + (bias ? bias[col] : 0.f);
                    if (OUTMODE == 2) {
                        int hh = col >> 5, cc = col & 31;
                        ((u16*)Cout)[(((size_t)vi * 8 + hh) * S_N + si) * 32 + cc] = ftof16(v);
                    } else if (OUTMODE == 1) {
                        ((u16*)Cout)[(size_t)row * 256 + col] = ftof16(v);
                    } else {
                        ((float*)Cout)[(size_t)row * 256 + col] = v;
                    }
                }
            }
        }
    }
}

template <int AIN, int RELU, int OUTMODE, int SM32>
__global__ __launch_bounds__(256) void mgemm_k(
    const void* __restrict__ A, const u16* __restrict__ WhT, const u16* __restrict__ WlT,
    const float* __restrict__ bias, const float* __restrict__ bias2,
    void* __restrict__ Cout, int M, int N, int K)
{
    __shared__ u16 smem[15360];
    gemm_body<AIN, RELU, OUTMODE, 0, SM32>(A, WhT, WlT, bias, bias2, Cout,
                                           M, N, K, blockIdx.x, blockIdx.y,
                                           smem, smem + 2560, smem + 5120, smem + 10240);
}

template <int AIN, int OUTMODE, int LN>
__global__ __launch_bounds__(256) void gemm256_k(
    const void* __restrict__ A, const u16* __restrict__ WhT, const u16* __restrict__ WlT,
    const float* __restrict__ bias, const float* __restrict__ res,
    const float* __restrict__ gam, const float* __restrict__ bet,
    void* __restrict__ Cout, int M, int K)
{
    __shared__ u16 smem[25600];
    gemm_body256<AIN, OUTMODE, LN>(A, WhT, WlT, bias, res, gam, bet, Cout, M, K,
                                   blockIdx.y, smem);
}

// fused head: fmaps->val(head-major f16) | q->vcur | hist->vhist | q@Wc->owt(+sm4)
__global__ __launch_bounds__(256) void fused3_k(
    const float* __restrict__ fmaps, const float* __restrict__ q, const float* __restrict__ hist,
    const u16* __restrict__ Wv_s_h, const u16* __restrict__ Wv_s_l,
    const u16* __restrict__ Wv_t_h, const u16* __restrict__ Wv_t_l,
    const u16* __restrict__ Wc_h,   const u16* __restrict__ Wc_l,
    const float* __restrict__ bc,
    u16* __restrict__ val_hm, u16* __restrict__ vcur, u16* __restrict__ vhist,
    float* __restrict__ owt)
{
    __shared__ u16 smem[25600];
    const int b = blockIdx.x;
    if (b < 749) {
        gemm_body256<0, 2, 0>(fmaps, Wv_s_h, Wv_s_l, nullptr, nullptr, nullptr, nullptr,
                              val_hm, 47874, 256, b, smem);
    } else if (b < 849) {
        gemm_body256<0, 1, 0>(q, Wv_t_h, Wv_t_l, nullptr, nullptr, nullptr, nullptr,
                              vcur, 6400, 256, b - 749, smem);
    } else if (b < 949) {
        gemm_body256<0, 1, 0>(hist, Wv_t_h, Wv_t_l, nullptr, nullptr, nullptr, nullptr,
                              vhist, 6400, 256, b - 849, smem);
    } else {
        gemm_body<0, 0, 0, 1, 0>(q, Wc_h, Wc_l, bc, nullptr, owt,
                                 6400, 128, 256, 0, b - 949,
                                 smem, smem + 2560, smem + 5120, smem + 10240);
    }
}

// =================== weight prep (unchanged) ===================
__global__ __launch_bounds__(256) void wprep_k(
    const float* __restrict__ w0, const float* __restrict__ w1, const float* __restrict__ w2,
    const float* __restrict__ w3, const float* __restrict__ w4, const float* __restrict__ w5,
    const float* __restrict__ w6, const float* __restrict__ w7, u16* __restrict__ base,
    const float* __restrict__ Woff_t, const float* __restrict__ Ww_t,
    const float* __restrict__ boff_t, const float* __restrict__ bw_t,
    float* __restrict__ bc)
{
    const int b = blockIdx.x, tid = threadIdx.x;
    if (b == 184) {
        if (tid < 128) bc[tid] = (tid < 64) ? boff_t[tid] : (tid < 96 ? bw_t[tid - 64] : 0.f);
        return;
    }
    const int cum[10]  = {0, 16, 32, 48, 80, 96, 112, 144, 176, 184};
    const int Ks[9]    = {256, 256, 256, 256, 256, 256, 256, 512, 256};
    const int Ns[9]    = {256, 256, 256, 512, 256, 256, 512, 256, 128};
    const int hoff[9]  = {0, 131072, 262144, 393216, 524288, 786432, 917504, 1179648, 1441792};
    const int loff[9]  = {65536, 196608, 327680, 589824, 720896, 851968, 1048576, 1310720, 1474560};
    int seg = 0;
    #pragma unroll
    for (int s = 1; s < 9; ++s) if (b >= cum[s]) seg = s;
    const int K = Ks[seg], N = Ns[seg];
    const int t = b - cum[seg];
    const int ntn = N / 64;
    const int k0 = (t / ntn) * 64, n0 = (t % ntn) * 64;
    __shared__ float tile[64][65];
    const int rr = tid >> 2, cc = (tid & 3) * 16;
    if (seg < 8) {
        const float* W = seg == 0 ? w0 : seg == 1 ? w1 : seg == 2 ? w2 : seg == 3 ? w3 :
                         seg == 4 ? w4 : seg == 5 ? w5 : seg == 6 ? w6 : w7;
        #pragma unroll
        for (int c = 0; c < 4; ++c) {
            float4 v = *(const float4*)(W + (size_t)(k0 + rr) * N + n0 + cc + c * 4);
            tile[rr][cc + c * 4 + 0] = v.x;
            tile[rr][cc + c * 4 + 1] = v.y;
            tile[rr][cc + c * 4 + 2] = v.z;
            tile[rr][cc + c * 4 + 3] = v.w;
        }
    } else {
        #pragma unroll
        for (int i = 0; i < 16; ++i) {
            int n = n0 + cc + i, k = k0 + rr;
            float v = (n < 64) ? Woff_t[k * 64 + n] : (n < 96 ? Ww_t[k * 32 + n - 64] : 0.f);
            tile[rr][cc + i] = v;
        }
    }
    __syncthreads();
    const int nr = tid >> 2, kc = (tid & 3) * 16;
    u16 hb[16], lb[16];
    #pragma unroll
    for (int i = 0; i < 16; ++i) {
        float v = tile[kc + i][nr];
        hb[i] = bfrn(v);
        lb[i] = bfrn(v - ubf(hb[i]));
    }
    u16* hp = base + hoff[seg] + (size_t)(n0 + nr) * K + k0 + kc;
    u16* lp = base + loff[seg] + (size_t)(n0 + nr) * K + k0 + kc;
    *(ushort4*)(hp + 0)  = *(ushort4*)&hb[0];
    *(ushort4*)(hp + 4)  = *(ushort4*)&hb[4];
    *(ushort4*)(hp + 8)  = *(ushort4*)&hb[8];
    *(ushort4*)(hp + 12) = *(ushort4*)&hb[12];
    *(ushort4*)(lp + 0)  = *(ushort4*)&lb[0];
    *(ushort4*)(lp + 4)  = *(ushort4*)&lb[4];
    *(ushort4*)(lp + 8)  = *(ushort4*)&lb[8];
    *(ushort4*)(lp + 12) = *(ushort4*)&lb[12];
}

// =================== bilinear (f16 source row-major, 4ch) for temporal ===================
__device__ __forceinline__ float4 bilin4h(const u16* __restrict__ v, int H, int W,
                                          float x, float y, int chb)
{
    float xf = floorf(x), yf = floorf(y);
    int x0 = (int)xf, y0 = (int)yf;
    int x1 = x0 + 1, y1 = y0 + 1;
    float fx = x - xf, fy = y - yf;
    float w00 = (1.f - fx) * (1.f - fy), w10 = fx * (1.f - fy);
    float w01 = (1.f - fx) * fy,         w11 = fx * fy;
    bool xi0 = (x0 >= 0) && (x0 < W);
    bool xi1 = (x1 >= 0) && (x1 < W);
    bool yi0 = (y0 >= 0) && (y0 < H);
    bool yi1 = (y1 >= 0) && (y1 < H);
    float4 r = make_float4(0.f, 0.f, 0.f, 0.f);
    #define CORNER(xi, yi, xx, yy, ww)                                           \
        if ((yi) && (xi)) {                                                      \
            uint2 u = *(const uint2*)(v + ((size_t)(yy) * W + (xx)) * 256 + chb);\
            float2 f0 = __half22float2(*(const __half2*)&u.x);                   \
            float2 f1 = __half22float2(*(const __half2*)&u.y);                   \
            r.x += (ww) * f0.x; r.y += (ww) * f0.y;                              \
            r.z += (ww) * f1.x; r.w += (ww) * f1.y;                              \
        }
    CORNER(xi0, yi0, x0, y0, w00)
    CORNER(xi1, yi0, x1, y0, w10)
    CORNER(xi0, yi1, x0, y1, w01)
    CORNER(xi1, yi1, x1, y1, w11)
    #undef CORNER
    return r;
}

// =================== temporal deformable attention ===================
__global__ __launch_bounds__(256) void temporal_k(
    const u16* __restrict__ vcur, const u16* __restrict__ vhist,
    const float* __restrict__ ow, const float* __restrict__ Tm, float* __restrict__ outt)
{
    const int b = blockIdx.x;
    const int q = (b & 7) * 800 + (b >> 3);
    const int tid = threadIdx.x;
    const int c4 = tid & 63, rep = tid >> 6;
    const int br = rep >> 1, p = rep & 1;
    const int h = c4 >> 3;
    const int chb = h * 32 + (c4 & 7) * 4;
    const int jx = q % BEV, iy = q / BEV;
    const float refx = (jx + 0.5f) / 80.f;
    const float refy = (iy + 0.5f) / 80.f;
    const float wx = (refx - 0.5f) * 40.96f;
    const float wy = (refy - 0.5f) * 40.96f;
    float bx, by;
    const u16* v;
    if (br == 0) { v = vcur; bx = refx; by = refy; }
    else {
        float h0 = Tm[0] * wx + Tm[1] * wy + Tm[2];
        float h1 = Tm[3] * wx + Tm[4] * wy + Tm[5];
        float h2 = Tm[6] * wx + Tm[7] * wy + Tm[8];
        v = vhist;
        bx = h0 / h2 / 40.96f + 0.5f;
        by = h1 / h2 / 40.96f + 0.5f;
    }
    const float* owq = ow + (size_t)q * 128;
    int ob = h * 8 + br * 4 + p * 2;
    float lx = bx + owq[ob] * (1.f / 80.f);
    float ly = by + owq[ob + 1] * (1.f / 80.f);
    float wgt = owq[64 + h * 4 + br * 2 + p];
    float4 sv = bilin4h(v, BEV, BEV, lx * 80.f - 0.5f, ly * 80.f - 0.5f, chb);
    __shared__ float4 s_acc[4][64];
    s_acc[rep][c4] = make_float4(wgt * sv.x, wgt * sv.y, wgt * sv.z, wgt * sv.w);
    __syncthreads();
    if (rep == 0) {
        float4 a = s_acc[0][c4], b2 = s_acc[1][c4], c = s_acc[2][c4], d = s_acc[3][c4];
        float4 o = make_float4(a.x + b2.x + c.x + d.x, a.y + b2.y + c.y + d.y,
                               a.z + b2.z + c.z + d.z, a.w + b2.w + c.w + d.w);
        *(float4*)(outt + (size_t)q * 256 + c4 * 4) = o;
    }
}

// =================== spatial deformable attention (head-major f16 val) ===================
// Lane = (h=lane>>3, xsel=(lane>>2)&1, c8=(lane&3)*8). One (vz,l,p) unit per wave
// per step; x-corner pair = contiguous 128B; y-rows = 2 loads. Units round-robin
// over 4 waves.
__global__ __launch_bounds__(256) void spatial_k(
    const u16* __restrict__ val, const u16* __restrict__ ow,
    const float* __restrict__ cam, const float* __restrict__ zrefs,
    float* __restrict__ out)
{
    const int b = blockIdx.x;
    const int q = (b & 7) * 800 + (b >> 3);
    const int tid = threadIdx.x;
    const int lane = tid & 63, wave = tid >> 6;
    const int h = lane >> 3, sub = lane & 7;
    const int xsel = sub >> 2, c8 = (sub & 3) * 8;
    __shared__ float s_un[24], s_vn[24], s_ok[24];
    __shared__ int s_list[24];
    __shared__ int s_n;
    __shared__ float s_cnt;
    __shared__ float s_ox[256], s_oy[256], s_wt[256];  // [pk=z*8+l*2+p][h]
    __shared__ float s_part[4][256];
    const int jx = q % BEV, iy = q / BEV;
    const float wxw = ((jx + 0.5f) / 80.f - 0.5f) * 40.96f;
    const float wyw = ((iy + 0.5f) / 80.f - 0.5f) * 40.96f;
    if (tid < 24) {
        int v = tid >> 2, zz = tid & 3;
        float zr = zrefs[zz];
        const float* P = cam + v * 12;
        float u0 = P[0] * wxw + P[1] * wyw + P[2] * zr + P[3];
        float u1 = P[4] * wxw + P[5] * wyw + P[6] * zr + P[7];
        float dd = P[8] * wxw + P[9] * wyw + P[10] * zr + P[11];
        float dm = fmaxf(dd, 1e-5f);
        float un = u0 / dm / 800.f;
        float vn = u1 / dm / 480.f;
        bool ok = (dd > 1e-5f) && (un >= 0.f) && (un <= 1.f) && (vn >= 0.f) && (vn <= 1.f);
        s_un[tid] = un; s_vn[tid] = vn; s_ok[tid] = ok ? 1.f : 0.f;
    }
    {
        const u16* owq = ow + (size_t)q * 768;
        #pragma unroll
        for (int rep = 0; rep < 2; ++rep) {
            int flat = tid + rep * 256;
            int hh = flat >> 6, rem = flat & 63;
            int zz = rem >> 4, ll = (rem >> 2) & 3, pp = (rem >> 1) & 1, xy = rem & 1;
            int dst = (zz * 8 + ll * 2 + pp) * 8 + hh;
            float v = f16tof(owq[flat]);
            if (xy) s_oy[dst] = v; else s_ox[dst] = v;
        }
        int hh = tid >> 5, rem = tid & 31;
        s_wt[rem * 8 + hh] = f16tof(owq[512 + tid]);
    }
    __syncthreads();
    if (tid == 0) {
        int n = 0; float c = 0.f;
        for (int vz = 0; vz < 24; ++vz) {
            if (s_ok[vz] != 0.f) { s_list[n++] = vz; c += 1.f; }
        }
        s_n = n; s_cnt = fmaxf(c, 1.f);
    }
    __syncthreads();
    const int nu = s_n * 8;
    const int LH[4] = {60, 30, 15, 8};
    const int LW[4] = {100, 50, 25, 13};
    const int LS[4] = {0, 6000, 7500, 7875};
    float a0 = 0.f, a1 = 0.f, a2 = 0.f, a3 = 0.f, a4 = 0.f, a5 = 0.f, a6 = 0.f, a7 = 0.f;
    for (int it = wave; it < nu; it += 4) {
        const int vz = s_list[it >> 3];
        const int lp = it & 7, l = lp >> 1, p = lp & 1;
        const int v = vz >> 2, z = vz & 3;
        const int Hl = LH[l], Wl = LW[l];
        const int idx = (z * 8 + l * 2 + p) * 8 + h;
        float x = s_un[vz] * Wl - 0.5f + s_ox[idx];
        float y = s_vn[vz] * Hl - 0.5f + s_oy[idx];
        float wgt = s_wt[idx];
        float xf = floorf(x), yf = floorf(y);
        int x0 = (int)xf, y0 = (int)yf;
        float fx = x - xf, fy = y - yf;
        int xi = x0 + xsel;
        float wxc = xsel ? fx : (1.f - fx);
        if (xi < 0 || xi >= Wl) wxc = 0.f;
        int xc = min(max(xi, 0), Wl - 1);
        float wy0 = (y0 >= 0 && y0 < Hl) ? (1.f - fy) : 0.f;
        float wy1 = (y0 + 1 >= 0 && y0 + 1 < Hl) ? fy : 0.f;
        int y0c = min(max(y0, 0), Hl - 1);
        int y1c = min(max(y0 + 1, 0), Hl - 1);
        const u16* base = val + (((size_t)v * 8 + h) * S_N + LS[l]) * 32 + c8;
        uint4 u0 = *(const uint4*)(base + ((size_t)y0c * Wl + xc) * 32);
        uint4 u1 = *(const uint4*)(base + ((size_t)y1c * Wl + xc) * 32);
        float wA = wgt * wxc * wy0, wB = wgt * wxc * wy1;
        const __half2* p0 = (const __half2*)&u0;
        const __half2* p1 = (const __half2*)&u1;
        float2 f;
        f = __half22float2(p0[0]); a0 += wA * f.x; a1 += wA * f.y;
        f = __half22float2(p0[1]); a2 += wA * f.x; a3 += wA * f.y;
        f = __half22float2(p0[2]); a4 += wA * f.x; a5 += wA * f.y;
        f = __half22float2(p0[3]); a6 += wA * f.x; a7 += wA * f.y;
        f = __half22float2(p1[0]); a0 += wB * f.x; a1 += wB * f.y;
        f = __half22float2(p1[1]); a2 += wB * f.x; a3 += wB * f.y;
        f = __half22float2(p1[2]); a4 += wB * f.x; a5 += wB * f.y;
        f = __half22float2(p1[3]); a6 += wB * f.x; a7 += wB * f.y;
    }
    // combine x-corner pairs (lane ^ 4 keeps h, flips xsel)
    a0 += __shfl_xor(a0, 4); a1 += __shfl_xor(a1, 4);
    a2 += __shfl_xor(a2, 4); a3 += __shfl_xor(a3, 4);
    a4 += __shfl_xor(a4, 4); a5 += __shfl_xor(a5, 4);
    a6 += __shfl_xor(a6, 4); a7 += __shfl_xor(a7, 4);
    if (xsel == 0) {
        *(float4*)&s_part[wave][h * 32 + c8]     = make_float4(a0, a1, a2, a3);
        *(float4*)&s_part[wave][h * 32 + c8 + 4] = make_float4(a4, a5, a6, a7);
    }
    __syncthreads();
    float sum = s_part[0][tid] + s_part[1][tid] + s_part[2][tid] + s_part[3][tid];
    out[(size_t)q * 256 + tid] = sum / s_cnt;
}

extern "C" void kernel_launch(void* const* d_in, const int* in_sizes, int n_in,
                              void* d_out, int out_size, void* d_ws, size_t ws_size,
                              hipStream_t stream) {
    (void)in_sizes; (void)n_in; (void)out_size; (void)ws_size;
    const float* q      = (const float*)d_in[0];
    const float* hist   = (const float*)d_in[1];
    const float* fmaps  = (const float*)d_in[2];
    const float* Tm     = (const float*)d_in[3];
    const float* zrefs  = (const float*)d_in[4];
    const float* cam    = (const float*)d_in[5];
    const float* Woff_t = (const float*)d_in[7];
    const float* boff_t = (const float*)d_in[8];
    const float* Ww_t   = (const float*)d_in[9];
    const float* bw_t   = (const float*)d_in[10];
    const float* bo_t   = (const float*)d_in[12];
    const float* ln1g   = (const float*)d_in[13];
    const float* ln1b   = (const float*)d_in[14];
    const float* boff_s = (const float*)d_in[17];
    const float* bw_s   = (const float*)d_in[19];
    const float* bo_s   = (const float*)d_in[21];
    const float* ln2g   = (const float*)d_in[22];
    const float* ln2b   = (const float*)d_in[23];
    const float* b1     = (const float*)d_in[25];
    const float* b2     = (const float*)d_in[27];
    const float* ln3g   = (const float*)d_in[28];
    const float* ln3b   = (const float*)d_in[29];

    float* ws    = (float*)d_ws;
    float* r4    = ws;                    // out_t / sampled-out consumer scratch
    float* out2  = ws + 1638400;
    float* r0    = ws + 3276800;          // out1-target unused; sampled
    float* out4  = ws + 4915200;
    float* owt   = ws + 6553600;          // 6400x128 f32
    u16*  r5u    = (u16*)(ws + 7372800);  // off_s|w_s f16 6400x768
    u16*  valhm  = (u16*)(ws + 9830400);  // head-major val f16 (12,255,744 u16)
    u16*  vcur   = (u16*)(ws + 15958400);
    u16*  vhist  = (u16*)(ws + 16777600);
    u16*  wtab   = (u16*)(ws + 17596800);
    float* bc    = ws + 18350464;

    u16* hidden = valhm;  // reuse after spatial
    u16* Wv_t_h = wtab + 0,       *Wv_t_l = wtab + 65536;
    u16* Wo_t_h = wtab + 131072,  *Wo_t_l = wtab + 196608;
    u16* Wv_s_h = wtab + 262144,  *Wv_s_l = wtab + 327680;
    u16* Comb_h = wtab + 393216,  *Comb_l = wtab + 589824;
    u16* Wo_s_h = wtab + 786432,  *Wo_s_l = wtab + 851968;
    u16* W1_h   = wtab + 917504,  *W1_l   = wtab + 1048576;
    u16* W2_h   = wtab + 1179648, *W2_l   = wtab + 1310720;
    u16* Wc_h   = wtab + 1441792, *Wc_l   = wtab + 1474560;

    dim3 blk(256);

    // 1) weight prep
    wprep_k<<<dim3(185), blk, 0, stream>>>(
        (const float*)d_in[6], (const float*)d_in[11], (const float*)d_in[15],
        (const float*)d_in[16], (const float*)d_in[18], (const float*)d_in[20],
        (const float*)d_in[24], (const float*)d_in[26], wtab,
        Woff_t, Ww_t, boff_t, bw_t, bc);
    // 2) fused head GEMMs
    fused3_k<<<dim3(1049), blk, 0, stream>>>(
        fmaps, q, hist, Wv_s_h, Wv_s_l, Wv_t_h, Wv_t_l, Wc_h, Wc_l, bc,
        valhm, vcur, vhist, owt);
    // 3) temporal sampling -> r4
    temporal_k<<<dim3(6400), blk, 0, stream>>>(vcur, vhist, owt, Tm, r4);
    // 4) out2 = LN1(out_t @ Wo_t + bo_t + q)
    gemm256_k<0,0,1><<<dim3(1, 100), blk, 0, stream>>>(
        r4, Wo_t_h, Wo_t_l, bo_t, q, ln1g, ln1b, out2, 6400, 256);
    // 5) off_s|w_s combined -> f16 (softmax32 fused on cols>=512)
    mgemm_k<0,0,1,1><<<dim3(6, 100), blk, 0, stream>>>(
        out2, Comb_h, Comb_l, boff_s, bw_s, r5u, 6400, 768, 256);
    // 6) spatial sampling -> r0
    spatial_k<<<dim3(6400), blk, 0, stream>>>(valhm, r5u, cam, zrefs, r0);
    // 7) out4 = LN2(sampled @ Wo_s + bo_s + out2)
    gemm256_k<0,0,1><<<dim3(1, 100), blk, 0, stream>>>(
        r0, Wo_s_h, Wo_s_l, bo_s, out2, ln2g, ln2b, out4, 6400, 256);
    // 8) hidden = relu(out4 @ W1 + b1) -> f16
    mgemm_k<0,1,1,0><<<dim3(4, 100), blk, 0, stream>>>(
        out4, W1_h, W1_l, b1, nullptr, hidden, 6400, 512, 256);
    // 9) out = LN3(hidden @ W2 + b2 + out4)
    gemm256_k<1,0,1><<<dim3(1, 100), blk, 0, stream>>>(
        hidden, W2_h, W2_l, b2, out4, ln3g, ln3b, (float*)d_out, 6400, 512);
}

// Round 9
// 360.471 us; speedup vs baseline: 1.1006x; 1.1006x over previous
//
#include <hip/hip_runtime.h>
#include <hip/hip_bf16.h>
#include <hip/hip_fp16.h>

typedef unsigned short u16;
typedef unsigned int u32;
typedef __attribute__((ext_vector_type(8))) short bf16x8;
typedef __attribute__((ext_vector_type(4))) float f32x4;

#define Q_N  6400
#define S_N  7979
#define BEV  80

__device__ __forceinline__ float ubf(u16 u) {
    return __uint_as_float(((u32)u) << 16);
}
__device__ __forceinline__ u16 bfrn(float x) {
    u32 b = __float_as_uint(x);
    return (u16)((b + 0x7FFFu + ((b >> 16) & 1u)) >> 16);
}
__device__ __forceinline__ float f16tof(u16 u) {
    __half h; *(u16*)&h = u; return __half2float(h);
}
__device__ __forceinline__ u16 ftof16(float f) {
    __half h = __float2half(f); return *(u16*)&h;
}

// =================== BN=128 GEMM body (BM=64, BK=32) ===================
template <int AIN, int RELU, int OUTMODE, int SM4, int SM32>
__device__ __forceinline__ void gemm_body(
    const void* __restrict__ A, const u16* __restrict__ WhT, const u16* __restrict__ WlT,
    const float* __restrict__ bias, const float* __restrict__ bias2,
    void* __restrict__ Cout, int M, int N, int K, int bx, int by,
    u16* Ah, u16* Al, u16* Wh, u16* Wl)
{
    const int tid  = threadIdx.x;
    const int lane = tid & 63;
    const int wave = tid >> 6;
    const int wm = (wave >> 1) * 32, wn = (wave & 1) * 64;
    const int m0 = by * 64, n0 = bx * 128;
    const int arow = tid >> 2, ak = (tid & 3) * 8;
    const int wrow = tid >> 1, wk = (tid & 1) * 16;
    const int fr = lane & 15, gq = lane >> 4;

    f32x4 acc[8];
    #pragma unroll
    for (int i = 0; i < 8; ++i) acc[i] = (f32x4)(0.f);

    for (int k0 = 0; k0 < K; k0 += 32) {
        {
            const bool okr = (m0 + arow) < M;
            float vals[8];
            if (AIN == 0) {
                const float* ap = (const float*)A + (size_t)(m0 + arow) * K + k0 + ak;
                float4 v0 = okr ? *(const float4*)(ap)     : make_float4(0.f, 0.f, 0.f, 0.f);
                float4 v1 = okr ? *(const float4*)(ap + 4) : make_float4(0.f, 0.f, 0.f, 0.f);
                vals[0] = v0.x; vals[1] = v0.y; vals[2] = v0.z; vals[3] = v0.w;
                vals[4] = v1.x; vals[5] = v1.y; vals[6] = v1.z; vals[7] = v1.w;
            } else {
                const u16* ap = (const u16*)A + (size_t)(m0 + arow) * K + k0 + ak;
                uint4 u = okr ? *(const uint4*)ap : make_uint4(0, 0, 0, 0);
                const __half2* hp = (const __half2*)&u;
                #pragma unroll
                for (int i = 0; i < 4; ++i) {
                    float2 f = __half22float2(hp[i]);
                    vals[2 * i] = f.x; vals[2 * i + 1] = f.y;
                }
            }
            u16 hb[8], lb[8];
            #pragma unroll
            for (int i = 0; i < 8; ++i) {
                hb[i] = bfrn(vals[i]);
                lb[i] = bfrn(vals[i] - ubf(hb[i]));
            }
            *(ushort4*)(&Ah[arow * 40 + ak])     = *(ushort4*)&hb[0];
            *(ushort4*)(&Ah[arow * 40 + ak + 4]) = *(ushort4*)&hb[4];
            *(ushort4*)(&Al[arow * 40 + ak])     = *(ushort4*)&lb[0];
            *(ushort4*)(&Al[arow * 40 + ak + 4]) = *(ushort4*)&lb[4];
        }
        {
            const size_t wo = (size_t)(n0 + wrow) * K + k0 + wk;
            *(uint4*)&Wh[wrow * 40 + wk]     = *(const uint4*)(WhT + wo);
            *(uint4*)&Wh[wrow * 40 + wk + 8] = *(const uint4*)(WhT + wo + 8);
            *(uint4*)&Wl[wrow * 40 + wk]     = *(const uint4*)(WlT + wo);
            *(uint4*)&Wl[wrow * 40 + wk + 8] = *(const uint4*)(WlT + wo + 8);
        }
        __syncthreads();
        bf16x8 fah[2], fal[2], fwh[4], fwl[4];
        #pragma unroll
        for (int i = 0; i < 2; ++i) {
            fah[i] = *(const bf16x8*)&Ah[(wm + i * 16 + fr) * 40 + gq * 8];
            fal[i] = *(const bf16x8*)&Al[(wm + i * 16 + fr) * 40 + gq * 8];
        }
        #pragma unroll
        for (int j = 0; j < 4; ++j) {
            fwh[j] = *(const bf16x8*)&Wh[(wn + j * 16 + fr) * 40 + gq * 8];
            fwl[j] = *(const bf16x8*)&Wl[(wn + j * 16 + fr) * 40 + gq * 8];
        }
        #pragma unroll
        for (int i = 0; i < 2; ++i)
            #pragma unroll
            for (int j = 0; j < 4; ++j) {
                acc[i * 4 + j] = __builtin_amdgcn_mfma_f32_16x16x32_bf16(fah[i], fwh[j], acc[i * 4 + j], 0, 0, 0);
                acc[i * 4 + j] = __builtin_amdgcn_mfma_f32_16x16x32_bf16(fal[i], fwh[j], acc[i * 4 + j], 0, 0, 0);
                acc[i * 4 + j] = __builtin_amdgcn_mfma_f32_16x16x32_bf16(fah[i], fwl[j], acc[i * 4 + j], 0, 0, 0);
            }
        __syncthreads();
    }
    const int g4r = gq * 4;
    float bv[4];
    #pragma unroll
    for (int j = 0; j < 4; ++j) {
        int col = n0 + wn + j * 16 + fr;
        if (bias2) bv[j] = (col < 512) ? bias[col] : bias2[col - 512];
        else       bv[j] = bias ? bias[col] : 0.f;
    }
    const bool do_sm32 = SM32 && ((n0 + wn) >= 512);
    const bool do_sm4  = SM4 && (wn == 64);
    #pragma unroll
    for (int i = 0; i < 2; ++i) {
        #pragma unroll
        for (int r = 0; r < 4; ++r) {
            const int row = m0 + wm + i * 16 + g4r + r;
            float v0 = acc[i * 4 + 0][r] + bv[0];
            float v1 = acc[i * 4 + 1][r] + bv[1];
            float v2 = acc[i * 4 + 2][r] + bv[2];
            float v3 = acc[i * 4 + 3][r] + bv[3];
            if (RELU) {
                v0 = fmaxf(v0, 0.f); v1 = fmaxf(v1, 0.f);
                v2 = fmaxf(v2, 0.f); v3 = fmaxf(v3, 0.f);
            }
            if (SM4 && do_sm4) {
                float m0q = fmaxf(v0, __shfl_xor(v0, 1));
                m0q = fmaxf(m0q, __shfl_xor(m0q, 2));
                float e0 = __expf(v0 - m0q);
                float s0 = e0 + __shfl_xor(e0, 1);
                s0 += __shfl_xor(s0, 2);
                v0 = e0 / s0;
                float m1q = fmaxf(v1, __shfl_xor(v1, 1));
                m1q = fmaxf(m1q, __shfl_xor(m1q, 2));
                float e1 = __expf(v1 - m1q);
                float s1 = e1 + __shfl_xor(e1, 1);
                s1 += __shfl_xor(s1, 2);
                v1 = e1 / s1;
                v2 = 0.f; v3 = 0.f;
            }
            if (SM32 && do_sm32) {
                float ma = fmaxf(v0, v1);
                ma = fmaxf(ma, __shfl_xor(ma, 1));
                ma = fmaxf(ma, __shfl_xor(ma, 2));
                ma = fmaxf(ma, __shfl_xor(ma, 4));
                ma = fmaxf(ma, __shfl_xor(ma, 8));
                float e0 = __expf(v0 - ma), e1 = __expf(v1 - ma);
                float sa = e0 + e1;
                sa += __shfl_xor(sa, 1);
                sa += __shfl_xor(sa, 2);
                sa += __shfl_xor(sa, 4);
                sa += __shfl_xor(sa, 8);
                float ia = 1.f / sa;
                v0 = e0 * ia; v1 = e1 * ia;
                float mb = fmaxf(v2, v3);
                mb = fmaxf(mb, __shfl_xor(mb, 1));
                mb = fmaxf(mb, __shfl_xor(mb, 2));
                mb = fmaxf(mb, __shfl_xor(mb, 4));
                mb = fmaxf(mb, __shfl_xor(mb, 8));
                float e2 = __expf(v2 - mb), e3 = __expf(v3 - mb);
                float sb = e2 + e3;
                sb += __shfl_xor(sb, 1);
                sb += __shfl_xor(sb, 2);
                sb += __shfl_xor(sb, 4);
                sb += __shfl_xor(sb, 8);
                float ib = 1.f / sb;
                v2 = e2 * ib; v3 = e3 * ib;
            }
            if (row < M) {
                const int colb = n0 + wn + fr;
                if (OUTMODE == 1) {
                    u16* cp = (u16*)Cout + (size_t)row * N;
                    cp[colb]      = ftof16(v0);
                    cp[colb + 16] = ftof16(v1);
                    cp[colb + 32] = ftof16(v2);
                    cp[colb + 48] = ftof16(v3);
                } else {
                    float* cp = (float*)Cout + (size_t)row * N;
                    cp[colb]      = v0;
                    cp[colb + 16] = v1;
                    cp[colb + 32] = v2;
                    cp[colb + 48] = v3;
                }
            }
        }
    }
}

// =================== BN=256 GEMM body (BM=64, BK=32), N=256, row-major out ===================
// A staged once per K-tile (no BN-split re-read of A). OUTMODE: 0=f32, 1=f16.
template <int AIN, int OUTMODE>
__device__ __forceinline__ void gemm_body256(
    const void* __restrict__ A, const u16* __restrict__ WhT, const u16* __restrict__ WlT,
    const float* __restrict__ bias, void* __restrict__ Cout, int M, int K, int by, u16* smem)
{
    u16* Ah = smem;            // 64*40
    u16* Al = smem + 2560;     // 64*40
    u16* Wh = smem + 5120;     // 256*40
    u16* Wl = smem + 15360;    // 256*40
    const int tid  = threadIdx.x;
    const int lane = tid & 63;
    const int wave = tid >> 6;
    const int wm = (wave >> 1) * 32, wn = (wave & 1) * 128;
    const int m0 = by * 64;
    const int arow = tid >> 2, ak = (tid & 3) * 8;
    const int fr = lane & 15, gq = lane >> 4;

    f32x4 acc[16];
    #pragma unroll
    for (int i = 0; i < 16; ++i) acc[i] = (f32x4)(0.f);

    for (int k0 = 0; k0 < K; k0 += 32) {
        {
            const bool okr = (m0 + arow) < M;
            float vals[8];
            if (AIN == 0) {
                const float* ap = (const float*)A + (size_t)(m0 + arow) * K + k0 + ak;
                float4 v0 = okr ? *(const float4*)(ap)     : make_float4(0.f, 0.f, 0.f, 0.f);
                float4 v1 = okr ? *(const float4*)(ap + 4) : make_float4(0.f, 0.f, 0.f, 0.f);
                vals[0] = v0.x; vals[1] = v0.y; vals[2] = v0.z; vals[3] = v0.w;
                vals[4] = v1.x; vals[5] = v1.y; vals[6] = v1.z; vals[7] = v1.w;
            } else {
                const u16* ap = (const u16*)A + (size_t)(m0 + arow) * K + k0 + ak;
                uint4 u = okr ? *(const uint4*)ap : make_uint4(0, 0, 0, 0);
                const __half2* hp = (const __half2*)&u;
                #pragma unroll
                for (int i = 0; i < 4; ++i) {
                    float2 f = __half22float2(hp[i]);
                    vals[2 * i] = f.x; vals[2 * i + 1] = f.y;
                }
            }
            u16 hb[8], lb[8];
            #pragma unroll
            for (int i = 0; i < 8; ++i) {
                hb[i] = bfrn(vals[i]);
                lb[i] = bfrn(vals[i] - ubf(hb[i]));
            }
            *(ushort4*)(&Ah[arow * 40 + ak])     = *(ushort4*)&hb[0];
            *(ushort4*)(&Ah[arow * 40 + ak + 4]) = *(ushort4*)&hb[4];
            *(ushort4*)(&Al[arow * 40 + ak])     = *(ushort4*)&lb[0];
            *(ushort4*)(&Al[arow * 40 + ak + 4]) = *(ushort4*)&lb[4];
        }
        {
            const size_t wo = (size_t)tid * K + k0;
            const uint4* sh = (const uint4*)(WhT + wo);
            const uint4* sl = (const uint4*)(WlT + wo);
            uint4* dh = (uint4*)&Wh[tid * 40];
            uint4* dl = (uint4*)&Wl[tid * 40];
            dh[0] = sh[0]; dh[1] = sh[1]; dh[2] = sh[2]; dh[3] = sh[3];
            dl[0] = sl[0]; dl[1] = sl[1]; dl[2] = sl[2]; dl[3] = sl[3];
        }
        __syncthreads();
        bf16x8 fah[2], fal[2];
        #pragma unroll
        for (int i = 0; i < 2; ++i) {
            fah[i] = *(const bf16x8*)&Ah[(wm + i * 16 + fr) * 40 + gq * 8];
            fal[i] = *(const bf16x8*)&Al[(wm + i * 16 + fr) * 40 + gq * 8];
        }
        #pragma unroll
        for (int jg = 0; jg < 2; ++jg) {
            bf16x8 fwh[4], fwl[4];
            #pragma unroll
            for (int j = 0; j < 4; ++j) {
                fwh[j] = *(const bf16x8*)&Wh[(wn + jg * 64 + j * 16 + fr) * 40 + gq * 8];
                fwl[j] = *(const bf16x8*)&Wl[(wn + jg * 64 + j * 16 + fr) * 40 + gq * 8];
            }
            #pragma unroll
            for (int i = 0; i < 2; ++i)
                #pragma unroll
                for (int j = 0; j < 4; ++j) {
                    int a = i * 8 + jg * 4 + j;
                    acc[a] = __builtin_amdgcn_mfma_f32_16x16x32_bf16(fah[i], fwh[j], acc[a], 0, 0, 0);
                    acc[a] = __builtin_amdgcn_mfma_f32_16x16x32_bf16(fal[i], fwh[j], acc[a], 0, 0, 0);
                    acc[a] = __builtin_amdgcn_mfma_f32_16x16x32_bf16(fah[i], fwl[j], acc[a], 0, 0, 0);
                }
        }
        __syncthreads();
    }
    const int g4r = gq * 4;
    #pragma unroll
    for (int i = 0; i < 2; ++i) {
        #pragma unroll
        for (int r = 0; r < 4; ++r) {
            const int row = m0 + wm + i * 16 + g4r + r;
            if (row >= M) continue;
            #pragma unroll
            for (int j = 0; j < 8; ++j) {
                int col = wn + j * 16 + fr;
                float v = acc[i * 8 + j][r] + (bias ? bias[col] : 0.f);
                if (OUTMODE == 1) ((u16*)Cout)[(size_t)row * 256 + col] = ftof16(v);
                else              ((float*)Cout)[(size_t)row * 256 + col] = v;
            }
        }
    }
}

template <int AIN, int RELU, int OUTMODE, int SM32>
__global__ __launch_bounds__(256) void mgemm_k(
    const void* __restrict__ A, const u16* __restrict__ WhT, const u16* __restrict__ WlT,
    const float* __restrict__ bias, const float* __restrict__ bias2,
    void* __restrict__ Cout, int M, int N, int K)
{
    __shared__ u16 smem[15360];
    gemm_body<AIN, RELU, OUTMODE, 0, SM32>(A, WhT, WlT, bias, bias2, Cout,
                                           M, N, K, blockIdx.x, blockIdx.y,
                                           smem, smem + 2560, smem + 5120, smem + 10240);
}

// fused head: fmaps->val_f16 | q->vcur | hist->vhist | q@Wc->owt(+sm4), BN=256 bodies
__global__ __launch_bounds__(256) void fused3_k(
    const float* __restrict__ fmaps, const float* __restrict__ q, const float* __restrict__ hist,
    const u16* __restrict__ Wv_s_h, const u16* __restrict__ Wv_s_l,
    const u16* __restrict__ Wv_t_h, const u16* __restrict__ Wv_t_l,
    const u16* __restrict__ Wc_h,   const u16* __restrict__ Wc_l,
    const float* __restrict__ bc,
    u16* __restrict__ val_f16, u16* __restrict__ vcur, u16* __restrict__ vhist,
    float* __restrict__ owt)
{
    __shared__ u16 smem[25600];
    const int b = blockIdx.x;
    if (b < 749) {
        gemm_body256<0, 1>(fmaps, Wv_s_h, Wv_s_l, nullptr, val_f16, 47874, 256, b, smem);
    } else if (b < 849) {
        gemm_body256<0, 1>(q, Wv_t_h, Wv_t_l, nullptr, vcur, 6400, 256, b - 749, smem);
    } else if (b < 949) {
        gemm_body256<0, 1>(hist, Wv_t_h, Wv_t_l, nullptr, vhist, 6400, 256, b - 849, smem);
    } else {
        gemm_body<0, 0, 0, 1, 0>(q, Wc_h, Wc_l, bc, nullptr, owt,
                                 6400, 128, 256, 0, b - 949,
                                 smem, smem + 2560, smem + 5120, smem + 10240);
    }
}

// =================== weight prep ===================
__global__ __launch_bounds__(256) void wprep_k(
    const float* __restrict__ w0, const float* __restrict__ w1, const float* __restrict__ w2,
    const float* __restrict__ w3, const float* __restrict__ w4, const float* __restrict__ w5,
    const float* __restrict__ w6, const float* __restrict__ w7, u16* __restrict__ base,
    const float* __restrict__ Woff_t, const float* __restrict__ Ww_t,
    const float* __restrict__ boff_t, const float* __restrict__ bw_t,
    float* __restrict__ bc)
{
    const int b = blockIdx.x, tid = threadIdx.x;
    if (b == 184) {
        if (tid < 128) bc[tid] = (tid < 64) ? boff_t[tid] : (tid < 96 ? bw_t[tid - 64] : 0.f);
        return;
    }
    const int cum[10]  = {0, 16, 32, 48, 80, 96, 112, 144, 176, 184};
    const int Ks[9]    = {256, 256, 256, 256, 256, 256, 256, 512, 256};
    const int Ns[9]    = {256, 256, 256, 512, 256, 256, 512, 256, 128};
    const int hoff[9]  = {0, 131072, 262144, 393216, 524288, 786432, 917504, 1179648, 1441792};
    const int loff[9]  = {65536, 196608, 327680, 589824, 720896, 851968, 1048576, 1310720, 1474560};
    int seg = 0;
    #pragma unroll
    for (int s = 1; s < 9; ++s) if (b >= cum[s]) seg = s;
    const int K = Ks[seg], N = Ns[seg];
    const int t = b - cum[seg];
    const int ntn = N / 64;
    const int k0 = (t / ntn) * 64, n0 = (t % ntn) * 64;
    __shared__ float tile[64][65];
    const int rr = tid >> 2, cc = (tid & 3) * 16;
    if (seg < 8) {
        const float* W = seg == 0 ? w0 : seg == 1 ? w1 : seg == 2 ? w2 : seg == 3 ? w3 :
                         seg == 4 ? w4 : seg == 5 ? w5 : seg == 6 ? w6 : w7;
        #pragma unroll
        for (int c = 0; c < 4; ++c) {
            float4 v = *(const float4*)(W + (size_t)(k0 + rr) * N + n0 + cc + c * 4);
            tile[rr][cc + c * 4 + 0] = v.x;
            tile[rr][cc + c * 4 + 1] = v.y;
            tile[rr][cc + c * 4 + 2] = v.z;
            tile[rr][cc + c * 4 + 3] = v.w;
        }
    } else {
        #pragma unroll
        for (int i = 0; i < 16; ++i) {
            int n = n0 + cc + i, k = k0 + rr;
            float v = (n < 64) ? Woff_t[k * 64 + n] : (n < 96 ? Ww_t[k * 32 + n - 64] : 0.f);
            tile[rr][cc + i] = v;
        }
    }
    __syncthreads();
    const int nr = tid >> 2, kc = (tid & 3) * 16;
    u16 hb[16], lb[16];
    #pragma unroll
    for (int i = 0; i < 16; ++i) {
        float v = tile[kc + i][nr];
        hb[i] = bfrn(v);
        lb[i] = bfrn(v - ubf(hb[i]));
    }
    u16* hp = base + hoff[seg] + (size_t)(n0 + nr) * K + k0 + kc;
    u16* lp = base + loff[seg] + (size_t)(n0 + nr) * K + k0 + kc;
    *(ushort4*)(hp + 0)  = *(ushort4*)&hb[0];
    *(ushort4*)(hp + 4)  = *(ushort4*)&hb[4];
    *(ushort4*)(hp + 8)  = *(ushort4*)&hb[8];
    *(ushort4*)(hp + 12) = *(ushort4*)&hb[12];
    *(ushort4*)(lp + 0)  = *(ushort4*)&lb[0];
    *(ushort4*)(lp + 4)  = *(ushort4*)&lb[4];
    *(ushort4*)(lp + 8)  = *(ushort4*)&lb[8];
    *(ushort4*)(lp + 12) = *(ushort4*)&lb[12];
}

// =================== LayerNorm over 256 ===================
__global__ __launch_bounds__(256) void ln_k(
    const float* __restrict__ x, const float* __restrict__ res,
    const float* __restrict__ g, const float* __restrict__ b,
    float* __restrict__ out)
{
    const int row = blockIdx.x, t = threadIdx.x;
    const size_t idx = (size_t)row * 256 + t;
    float v = x[idx] + res[idx];
    float s = v, ss = v * v;
    #pragma unroll
    for (int o = 32; o > 0; o >>= 1) {
        s += __shfl_down(s, o);
        ss += __shfl_down(ss, o);
    }
    __shared__ float red[8];
    __shared__ float mv[2];
    const int wv = t >> 6, ln = t & 63;
    if (ln == 0) { red[wv] = s; red[4 + wv] = ss; }
    __syncthreads();
    if (t == 0) {
        float S = red[0] + red[1] + red[2] + red[3];
        float SS = red[4] + red[5] + red[6] + red[7];
        float mean = S * (1.f / 256.f);
        float var = SS * (1.f / 256.f) - mean * mean;
        mv[0] = mean;
        mv[1] = rsqrtf(var + 1e-5f);
    }
    __syncthreads();
    out[idx] = (v - mv[0]) * mv[1] * g[t] + b[t];
}

// =================== bilinear (f16 source row-major, 4ch) ===================
__device__ __forceinline__ float4 bilin4h(const u16* __restrict__ v, int H, int W,
                                          float x, float y, int chb)
{
    float xf = floorf(x), yf = floorf(y);
    int x0 = (int)xf, y0 = (int)yf;
    int x1 = x0 + 1, y1 = y0 + 1;
    float fx = x - xf, fy = y - yf;
    float w00 = (1.f - fx) * (1.f - fy), w10 = fx * (1.f - fy);
    float w01 = (1.f - fx) * fy,         w11 = fx * fy;
    bool xi0 = (x0 >= 0) && (x0 < W);
    bool xi1 = (x1 >= 0) && (x1 < W);
    bool yi0 = (y0 >= 0) && (y0 < H);
    bool yi1 = (y1 >= 0) && (y1 < H);
    float4 r = make_float4(0.f, 0.f, 0.f, 0.f);
    #define CORNER(xi, yi, xx, yy, ww)                                           \
        if ((yi) && (xi)) {                                                      \
            uint2 u = *(const uint2*)(v + ((size_t)(yy) * W + (xx)) * 256 + chb);\
            float2 f0 = __half22float2(*(const __half2*)&u.x);                   \
            float2 f1 = __half22float2(*(const __half2*)&u.y);                   \
            r.x += (ww) * f0.x; r.y += (ww) * f0.y;                              \
            r.z += (ww) * f1.x; r.w += (ww) * f1.y;                              \
        }
    CORNER(xi0, yi0, x0, y0, w00)
    CORNER(xi1, yi0, x1, y0, w10)
    CORNER(xi0, yi1, x0, y1, w01)
    CORNER(xi1, yi1, x1, y1, w11)
    #undef CORNER
    return r;
}

// =================== temporal deformable attention ===================
__global__ __launch_bounds__(256) void temporal_k(
    const u16* __restrict__ vcur, const u16* __restrict__ vhist,
    const float* __restrict__ ow, const float* __restrict__ Tm, float* __restrict__ outt)
{
    const int b = blockIdx.x;
    const int q = (b & 7) * 800 + (b >> 3);
    const int tid = threadIdx.x;
    const int c4 = tid & 63, rep = tid >> 6;
    const int br = rep >> 1, p = rep & 1;
    const int h = c4 >> 3;
    const int chb = h * 32 + (c4 & 7) * 4;
    const int jx = q % BEV, iy = q / BEV;
    const float refx = (jx + 0.5f) / 80.f;
    const float refy = (iy + 0.5f) / 80.f;
    const float wx = (refx - 0.5f) * 40.96f;
    const float wy = (refy - 0.5f) * 40.96f;
    float bx, by;
    const u16* v;
    if (br == 0) { v = vcur; bx = refx; by = refy; }
    else {
        float h0 = Tm[0] * wx + Tm[1] * wy + Tm[2];
        float h1 = Tm[3] * wx + Tm[4] * wy + Tm[5];
        float h2 = Tm[6] * wx + Tm[7] * wy + Tm[8];
        v = vhist;
        bx = h0 / h2 / 40.96f + 0.5f;
        by = h1 / h2 / 40.96f + 0.5f;
    }
    const float* owq = ow + (size_t)q * 128;
    int ob = h * 8 + br * 4 + p * 2;
    float lx = bx + owq[ob] * (1.f / 80.f);
    float ly = by + owq[ob + 1] * (1.f / 80.f);
    float wgt = owq[64 + h * 4 + br * 2 + p];
    float4 sv = bilin4h(v, BEV, BEV, lx * 80.f - 0.5f, ly * 80.f - 0.5f, chb);
    __shared__ float4 s_acc[4][64];
    s_acc[rep][c4] = make_float4(wgt * sv.x, wgt * sv.y, wgt * sv.z, wgt * sv.w);
    __syncthreads();
    if (rep == 0) {
        float4 a = s_acc[0][c4], b2 = s_acc[1][c4], c = s_acc[2][c4], d = s_acc[3][c4];
        float4 o = make_float4(a.x + b2.x + c.x + d.x, a.y + b2.y + c.y + d.y,
                               a.z + b2.z + c.z + d.z, a.w + b2.w + c.w + d.w);
        *(float4*)(outt + (size_t)q * 256 + c4 * 4) = o;
    }
}

// =================== spatial deformable attention (f16 val, (vz,l)-balanced) ===================
// 8 half-waves; each owns every-8th (vz,l) unit (n*4 units); lane = (head, 8-ch chunk).
__global__ __launch_bounds__(256) void spatial_k(
    const u16* __restrict__ val, const u16* __restrict__ ow,
    const float* __restrict__ cam, const float* __restrict__ zrefs,
    float* __restrict__ out)
{
    const int b = blockIdx.x;
    const int q = (b & 7) * 800 + (b >> 3);
    const int tid = threadIdx.x;
    const int lane = tid & 63, wave = tid >> 6;
    const int hw = lane >> 5, lh = lane & 31;
    const int slot = wave * 2 + hw;
    const int h = lh >> 2, chb = h * 32 + (lh & 3) * 8;
    __shared__ float s_un[24], s_vn[24], s_ok[24];
    __shared__ int s_list[24];
    __shared__ int s_n;
    __shared__ float s_cnt;
    __shared__ float s_ox[256], s_oy[256], s_wt[256];  // [pk=z*8+l*2+p][h]
    __shared__ float s_part[8][256];
    const int jx = q % BEV, iy = q / BEV;
    const float wxw = ((jx + 0.5f) / 80.f - 0.5f) * 40.96f;
    const float wyw = ((iy + 0.5f) / 80.f - 0.5f) * 40.96f;
    if (tid < 24) {
        int v = tid >> 2, zz = tid & 3;
        float zr = zrefs[zz];
        const float* P = cam + v * 12;
        float u0 = P[0] * wxw + P[1] * wyw + P[2] * zr + P[3];
        float u1 = P[4] * wxw + P[5] * wyw + P[6] * zr + P[7];
        float dd = P[8] * wxw + P[9] * wyw + P[10] * zr + P[11];
        float dm = fmaxf(dd, 1e-5f);
        float un = u0 / dm / 800.f;
        float vn = u1 / dm / 480.f;
        bool ok = (dd > 1e-5f) && (un >= 0.f) && (un <= 1.f) && (vn >= 0.f) && (vn <= 1.f);
        s_un[tid] = un; s_vn[tid] = vn; s_ok[tid] = ok ? 1.f : 0.f;
    }
    {
        const u16* owq = ow + (size_t)q * 768;
        #pragma unroll
        for (int rep = 0; rep < 2; ++rep) {
            int flat = tid + rep * 256;
            int hh = flat >> 6, rem = flat & 63;
            int zz = rem >> 4, ll = (rem >> 2) & 3, pp = (rem >> 1) & 1, xy = rem & 1;
            int dst = (zz * 8 + ll * 2 + pp) * 8 + hh;
            float v = f16tof(owq[flat]);
            if (xy) s_oy[dst] = v; else s_ox[dst] = v;
        }
        int hh = tid >> 5, rem = tid & 31;
        s_wt[rem * 8 + hh] = f16tof(owq[512 + tid]);
    }
    __syncthreads();
    if (tid == 0) {
        int n = 0; float c = 0.f;
        for (int vz = 0; vz < 24; ++vz) {
            if (s_ok[vz] != 0.f) { s_list[n++] = vz; c += 1.f; }
        }
        s_n = n; s_cnt = fmaxf(c, 1.f);
    }
    __syncthreads();
    const int nu = s_n * 4;    // (vz, l) units
    const int LH[4] = {60, 30, 15, 8};
    const int LW[4] = {100, 50, 25, 13};
    const int LS[4] = {0, 6000, 7500, 7875};
    float a0 = 0.f, a1 = 0.f, a2 = 0.f, a3 = 0.f, a4 = 0.f, a5 = 0.f, a6 = 0.f, a7 = 0.f;
    for (int it = slot; it < nu; it += 8) {
        const int vz = s_list[it >> 2];
        const int l = it & 3;
        const int v = vz >> 2, z = vz & 3;
        const int Hl = LH[l], Wl = LW[l];
        const u16* lv = val + ((size_t)v * S_N + LS[l]) * 256 + chb;
        const float unl = s_un[vz] * Wl - 0.5f, vnl = s_vn[vz] * Hl - 0.5f;
        #pragma unroll
        for (int p = 0; p < 2; ++p) {
            int idx = (z * 8 + l * 2 + p) * 8 + h;
            float x = unl + s_ox[idx];
            float y = vnl + s_oy[idx];
            float wgt = s_wt[idx];
            float xf = floorf(x), yf = floorf(y);
            int x0 = (int)xf, y0 = (int)yf;
            float fx = x - xf, fy = y - yf;
            __half2 w00 = __float2half2_rn((1.f - fx) * (1.f - fy) * wgt);
            __half2 w10 = __float2half2_rn(fx * (1.f - fy) * wgt);
            __half2 w01 = __float2half2_rn((1.f - fx) * fy * wgt);
            __half2 w11 = __float2half2_rn(fx * fy * wgt);
            bool xi0 = (x0 >= 0) && (x0 < Wl);
            bool xi1 = (x0 + 1 >= 0) && (x0 + 1 < Wl);
            bool yi0 = (y0 >= 0) && (y0 < Hl);
            bool yi1 = (y0 + 1 >= 0) && (y0 + 1 < Hl);
            const u16* r0p = lv + (size_t)y0 * (Wl * 256);
            const u16* r1p = r0p + (size_t)(Wl * 256);
            __half2 h0 = __float2half2_rn(0.f), h1 = h0, h2 = h0, h3 = h0;
            if (yi0 && xi0) {
                uint4 u = *(const uint4*)(r0p + (size_t)x0 * 256);
                const __half2* hp = (const __half2*)&u;
                h0 = __hfma2(w00, hp[0], h0); h1 = __hfma2(w00, hp[1], h1);
                h2 = __hfma2(w00, hp[2], h2); h3 = __hfma2(w00, hp[3], h3);
            }
            if (yi0 && xi1) {
                uint4 u = *(const uint4*)(r0p + (size_t)(x0 + 1) * 256);
                const __half2* hp = (const __half2*)&u;
                h0 = __hfma2(w10, hp[0], h0); h1 = __hfma2(w10, hp[1], h1);
                h2 = __hfma2(w10, hp[2], h2); h3 = __hfma2(w10, hp[3], h3);
            }
            if (yi1 && xi0) {
                uint4 u = *(const uint4*)(r1p + (size_t)x0 * 256);
                const __half2* hp = (const __half2*)&u;
                h0 = __hfma2(w01, hp[0], h0); h1 = __hfma2(w01, hp[1], h1);
                h2 = __hfma2(w01, hp[2], h2); h3 = __hfma2(w01, hp[3], h3);
            }
            if (yi1 && xi1) {
                uint4 u = *(const uint4*)(r1p + (size_t)(x0 + 1) * 256);
                const __half2* hp = (const __half2*)&u;
                h0 = __hfma2(w11, hp[0], h0); h1 = __hfma2(w11, hp[1], h1);
                h2 = __hfma2(w11, hp[2], h2); h3 = __hfma2(w11, hp[3], h3);
            }
            float2 f0 = __half22float2(h0), f1 = __half22float2(h1);
            float2 f2 = __half22float2(h2), f3 = __half22float2(h3);
            a0 += f0.x; a1 += f0.y; a2 += f1.x; a3 += f1.y;
            a4 += f2.x; a5 += f2.y; a6 += f3.x; a7 += f3.y;
        }
    }
    *(float4*)&s_part[slot][chb]     = make_float4(a0, a1, a2, a3);
    *(float4*)&s_part[slot][chb + 4] = make_float4(a4, a5, a6, a7);
    __syncthreads();
    float sum = 0.f;
    #pragma unroll
    for (int k = 0; k < 8; ++k) sum += s_part[k][tid];
    out[(size_t)q * 256 + tid] = sum / s_cnt;
}

extern "C" void kernel_launch(void* const* d_in, const int* in_sizes, int n_in,
                              void* d_out, int out_size, void* d_ws, size_t ws_size,
                              hipStream_t stream) {
    (void)in_sizes; (void)n_in; (void)out_size; (void)ws_size;
    const float* q      = (const float*)d_in[0];
    const float* hist   = (const float*)d_in[1];
    const float* fmaps  = (const float*)d_in[2];
    const float* Tm     = (const float*)d_in[3];
    const float* zrefs  = (const float*)d_in[4];
    const float* cam    = (const float*)d_in[5];
    const float* Woff_t = (const float*)d_in[7];
    const float* boff_t = (const float*)d_in[8];
    const float* Ww_t   = (const float*)d_in[9];
    const float* bw_t   = (const float*)d_in[10];
    const float* bo_t   = (const float*)d_in[12];
    const float* ln1g   = (const float*)d_in[13];
    const float* ln1b   = (const float*)d_in[14];
    const float* boff_s = (const float*)d_in[17];
    const float* bw_s   = (const float*)d_in[19];
    const float* bo_s   = (const float*)d_in[21];
    const float* ln2g   = (const float*)d_in[22];
    const float* ln2b   = (const float*)d_in[23];
    const float* b1     = (const float*)d_in[25];
    const float* b2     = (const float*)d_in[27];
    const float* ln3g   = (const float*)d_in[28];
    const float* ln3b   = (const float*)d_in[29];

    float* ws    = (float*)d_ws;
    float* r0    = ws;                   // sampled / out1 / out5
    float* r1    = ws + 1638400;         // out2
    float* owt   = ws + 3276800;         // offt|wt fp32, 6400x128
    float* r4    = ws + 4096000;         // out_t / out3
    u16*  r5u    = (u16*)(ws + 5734400); // off_s|w_s f16, 6400x768
    float* of4   = ws + 8192000;         // out4
    u16*  valbuf = (u16*)(ws + 9830400); // val_f16 12.25M u16 / hidden f16
    u16*  vcur   = (u16*)(ws + 15958272);
    u16*  vhist  = (u16*)(ws + 16777472);
    u16*  wtab   = (u16*)(ws + 17596672);
    float* bc    = ws + 18350336;

    u16* hidden = valbuf;
    u16* Wv_t_h = wtab + 0,       *Wv_t_l = wtab + 65536;
    u16* Wo_t_h = wtab + 131072,  *Wo_t_l = wtab + 196608;
    u16* Wv_s_h = wtab + 262144,  *Wv_s_l = wtab + 327680;
    u16* Comb_h = wtab + 393216,  *Comb_l = wtab + 589824;
    u16* Wo_s_h = wtab + 786432,  *Wo_s_l = wtab + 851968;
    u16* W1_h   = wtab + 917504,  *W1_l   = wtab + 1048576;
    u16* W2_h   = wtab + 1179648, *W2_l   = wtab + 1310720;
    u16* Wc_h   = wtab + 1441792, *Wc_l   = wtab + 1474560;

    dim3 blk(256);
    auto gm = [](int M, int N) { return dim3((unsigned)(N / 128), (unsigned)((M + 63) / 64)); };

    // 1) weight prep
    wprep_k<<<dim3(185), blk, 0, stream>>>(
        (const float*)d_in[6], (const float*)d_in[11], (const float*)d_in[15],
        (const float*)d_in[16], (const float*)d_in[18], (const float*)d_in[20],
        (const float*)d_in[24], (const float*)d_in[26], wtab,
        Woff_t, Ww_t, boff_t, bw_t, bc);
    // 2) fused head GEMMs (BN=256 bodies; fmaps read once)
    fused3_k<<<dim3(1049), blk, 0, stream>>>(
        fmaps, q, hist, Wv_s_h, Wv_s_l, Wv_t_h, Wv_t_l, Wc_h, Wc_l, bc,
        valbuf, vcur, vhist, owt);
    // 3) temporal sampling
    temporal_k<<<dim3(6400), blk, 0, stream>>>(vcur, vhist, owt, Tm, r4);
    // 4) out1 = out_t @ Wo_t + bo_t
    mgemm_k<0,0,0,0><<<gm(6400, 256), blk, 0, stream>>>(
        r4, Wo_t_h, Wo_t_l, bo_t, nullptr, r0, 6400, 256, 256);
    // 5) out2 = LN(out1 + q)
    ln_k<<<dim3(6400), blk, 0, stream>>>(r0, q, ln1g, ln1b, r1);
    // 6) off_s|w_s combined -> f16 (softmax32 fused on cols>=512)
    mgemm_k<0,0,1,1><<<gm(6400, 768), blk, 0, stream>>>(
        r1, Comb_h, Comb_l, boff_s, bw_s, r5u, 6400, 768, 256);
    // 7) spatial sampling
    spatial_k<<<dim3(6400), blk, 0, stream>>>(valbuf, r5u, cam, zrefs, r0);
    // 8) out3 = sampled @ Wo_s + bo_s
    mgemm_k<0,0,0,0><<<gm(6400, 256), blk, 0, stream>>>(
        r0, Wo_s_h, Wo_s_l, bo_s, nullptr, r4, 6400, 256, 256);
    // 9) out4 = LN(out3 + out2)
    ln_k<<<dim3(6400), blk, 0, stream>>>(r4, r1, ln2g, ln2b, of4);
    // 10) hidden = relu(out4 @ W1 + b1) -> f16
    mgemm_k<0,1,1,0><<<gm(6400, 512), blk, 0, stream>>>(
        of4, W1_h, W1_l, b1, nullptr, hidden, 6400, 512, 256);
    // 11) out5 = hidden @ W2 + b2
    mgemm_k<1,0,0,0><<<gm(6400, 256), blk, 0, stream>>>(
        hidden, W2_h, W2_l, b2, nullptr, r0, 6400, 256, 512);
    // 12) out = LN(out5 + out4)
    ln_k<<<dim3(6400), blk, 0, stream>>>(r0, of4, ln3g, ln3b, (float*)d_out);
}